// Round 6
// baseline (238.603 us; speedup 1.0000x reference)
//
#include <hip/hip_runtime.h>
#include <math.h>

// Problem constants
#define BB 4
#define SS 4096
#define DD 64
#define HH 16
#define PI_C 3.1415f

// ---------------------------------------------------------------------------
// ws layout (bytes):
//   0        : pkv   fp32 [8][64bh][z*64+x]   8,388,608
//   8388608  : pkvs  fp32 [8][64bh][z*64+x]   8,388,608
//   16777216 : pks   fp32 [8][64bh][128]        262,144   (ksum|kssum)
//   17039360 : kvb   bf16 [64bh][z*64+x]        524,288
//   17563648 : kvsb  bf16                       524,288
//   18087936 : ksums fp32 [64bh][128]            32,768
//   18120704 : wT    bf16 wq|wk|wv|wd x 65536   524,288
//   total ~18.6 MB
// ---------------------------------------------------------------------------

typedef __attribute__((ext_vector_type(8))) short short8;   // 8 x bf16 frag
typedef __attribute__((ext_vector_type(4))) float f32x4;    // MFMA C/D frag

#define MFMA(a, b, c) __builtin_amdgcn_mfma_f32_16x16x32_bf16(a, b, c, 0, 0, 0)

__device__ __forceinline__ short f2bf(float f) {
    union { float f; unsigned u; } v; v.f = f;
    unsigned r = v.u + 0x7FFFu + ((v.u >> 16) & 1u);   // round-to-nearest-even
    return (short)(r >> 16);
}
__device__ __forceinline__ float bf2f(short s) {
    union { unsigned u; float f; } v;
    v.u = ((unsigned)(unsigned short)s) << 16;
    return v.f;
}
__device__ __forceinline__ short8 cvt8(float4 a, float4 b) {
    short8 r;
    r[0] = f2bf(a.x); r[1] = f2bf(a.y); r[2] = f2bf(a.z); r[3] = f2bf(a.w);
    r[4] = f2bf(b.x); r[5] = f2bf(b.y); r[6] = f2bf(b.z); r[7] = f2bf(b.w);
    return r;
}
__device__ __forceinline__ float elu1(float x) { return x > 0.f ? x + 1.f : __expf(x); }
__device__ __forceinline__ void st4(short* p, short a, short b, short c, short d) {
    union { uint2 u; short s[4]; } x;
    x.s[0] = a; x.s[1] = b; x.s[2] = c; x.s[3] = d;
    *reinterpret_cast<uint2*>(p) = x.u;
}

// ---------------------------------------------------------------------------
// Transpose + bf16-convert weights: wq/wk/wv (64 x 1024) and dense_w (1024 x 64)
// into per-head [out_col][in_dim] layout so MFMA B-frags are contiguous 16B loads.
__global__ __launch_bounds__(256) void k_prep(
    const float* __restrict__ wq, const float* __restrict__ wk,
    const float* __restrict__ wv, const float* __restrict__ wd,
    short* __restrict__ dst)
{
    const int h = blockIdx.x, y = blockIdx.y, t = threadIdx.x;
    const float* src = (y == 0) ? wq : (y == 1) ? wk : (y == 2) ? wv : wd;
    const int rs = (y < 3) ? 1024 : 64;
    const size_t srcbase = (y < 3) ? (size_t)(h * 64) : (size_t)(h * 4096);
    short* dm = dst + (size_t)y * 65536 + (size_t)h * 4096;
#pragma unroll
    for (int j = 0; j < 4; ++j) {
        int idx = j * 1024 + t * 4;
        int r = idx >> 6, c = idx & 63;
        float4 v = *reinterpret_cast<const float4*>(src + (size_t)r * rs + srcbase + c);
        dm[(c + 0) * 64 + r] = f2bf(v.x);
        dm[(c + 1) * 64 + r] = f2bf(v.y);
        dm[(c + 2) * 64 + r] = f2bf(v.z);
        dm[(c + 3) * 64 + r] = f2bf(v.w);
    }
}

// ---------------------------------------------------------------------------
// Phase 1 (R2-exact, measured-good): project K,V (MFMA) -> transposed bf16
// tiles in DOUBLE-BUFFERED LDS so projection of tile t+1 and the kv GEMM of
// tile t share one barrier interval. kv/kvs GEMM uses SWAPPED operands
// (A=v, B=k') so C-layout is [z][x] -> coalesced non-atomic partial stores.
__global__ __launch_bounds__(256, 2) void k_phase1(
    const float* __restrict__ key, const float* __restrict__ value,
    const float* __restrict__ wk_b, const float* __restrict__ wv_b,
    const short* __restrict__ wkTb, const short* __restrict__ wvTb,
    float* __restrict__ pkv, float* __restrict__ pkvs,
    float* __restrict__ pks)
{
    const int chunk = blockIdx.x, h = blockIdx.y, b = blockIdx.z;
    const int t = threadIdx.x, w = t >> 6, l = t & 63;
    const int lane15 = l & 15, q8 = (l >> 4) * 8, q4 = (l >> 4) * 4;

    __shared__ short kT[2][64 * 72], vT[2][64 * 72], vsT[2][64 * 72];   // [buf][x|z][s]
    __shared__ float ssin[512];
    __shared__ float sbk[64], sbv[64];
    __shared__ float sred[512];

    // projection weight B-frags -> registers (once per block, L2-hot)
    short8 bkf[2][4], bvf[2][4];
    {
        const short* wkh = wkTb + (size_t)h * 4096;
        const short* wvh = wvTb + (size_t)h * 4096;
#pragma unroll
        for (int kss = 0; kss < 2; ++kss)
#pragma unroll
            for (int nt = 0; nt < 4; ++nt) {
                bkf[kss][nt] = *reinterpret_cast<const short8*>(wkh + (nt * 16 + lane15) * 64 + kss * 32 + q8);
                bvf[kss][nt] = *reinterpret_cast<const short8*>(wvh + (nt * 16 + lane15) * 64 + kss * 32 + q8);
            }
    }
    ssin[t]       = __sinf(PI_C * (float)(chunk * 512 + t)       * (1.f / 4096.f));
    ssin[t + 256] = __sinf(PI_C * (float)(chunk * 512 + t + 256) * (1.f / 4096.f));
    if (t < 64) sbk[t] = wk_b[h * 64 + t];
    else if (t < 128) sbv[t - 64] = wv_b[h * 64 + (t - 64)];

    // prefetch K/V rows for iter 0
    float4 kf0, kf1, kf2, kf3, vf0, vf1, vf2, vf3;
    {
        const size_t g = ((size_t)b * SS + chunk * 512 + w * 16 + lane15) * 64 + q8;
        kf0 = *reinterpret_cast<const float4*>(key + g);
        kf1 = *reinterpret_cast<const float4*>(key + g + 4);
        kf2 = *reinterpret_cast<const float4*>(key + g + 32);
        kf3 = *reinterpret_cast<const float4*>(key + g + 36);
        vf0 = *reinterpret_cast<const float4*>(value + g);
        vf1 = *reinterpret_cast<const float4*>(value + g + 4);
        vf2 = *reinterpret_cast<const float4*>(value + g + 32);
        vf3 = *reinterpret_cast<const float4*>(value + g + 36);
    }

    f32x4 ckv[4], ckvs[4];
#pragma unroll
    for (int i = 0; i < 4; ++i) {
        ckv[i]  = (f32x4){0.f, 0.f, 0.f, 0.f};
        ckvs[i] = (f32x4){0.f, 0.f, 0.f, 0.f};
    }
    float aks = 0.f, akss = 0.f;

    // projection + bias + act + transposed bf16 stores into buffer `buf`
    auto proj_store = [&](int buf, int sbase) {
        f32x4 ckp[4], cvp[4];
#pragma unroll
        for (int i = 0; i < 4; ++i) {
            ckp[i] = (f32x4){0.f, 0.f, 0.f, 0.f};
            cvp[i] = (f32x4){0.f, 0.f, 0.f, 0.f};
        }
        short8 ak0 = cvt8(kf0, kf1), ak1 = cvt8(kf2, kf3);
        short8 av0 = cvt8(vf0, vf1), av1 = cvt8(vf2, vf3);
#pragma unroll
        for (int nt = 0; nt < 4; ++nt) {
            ckp[nt] = MFMA(ak0, bkf[0][nt], ckp[nt]);
            cvp[nt] = MFMA(av0, bvf[0][nt], cvp[nt]);
            ckp[nt] = MFMA(ak1, bkf[1][nt], ckp[nt]);
            cvp[nt] = MFMA(av1, bvf[1][nt], cvp[nt]);
        }
        const int srel = w * 16 + q4;
#pragma unroll
        for (int nt = 0; nt < 4; ++nt) {
            const int x = nt * 16 + lane15;
            const float bk = sbk[x], bv = sbv[x];
            short ek[4], ev[4], es[4];
#pragma unroll
            for (int r = 0; r < 4; ++r) {
                float kk = elu1(ckp[nt][r] + bk);
                float vv = cvp[nt][r] + bv;
                ek[r] = f2bf(kk);
                ev[r] = f2bf(vv);
                es[r] = f2bf(vv * ssin[sbase + srel + r]);
            }
            st4(&kT [buf][x * 72 + srel], ek[0], ek[1], ek[2], ek[3]);
            st4(&vT [buf][x * 72 + srel], ev[0], ev[1], ev[2], ev[3]);
            st4(&vsT[buf][x * 72 + srel], es[0], es[1], es[2], es[3]);
        }
    };

    __syncthreads();           // ssin/sbk/sbv visible
    proj_store(0, 0);          // peeled: tile 0 -> buffer 0
    __syncthreads();           // buffer 0 complete

#pragma unroll 1
    for (int it = 0; it < 8; ++it) {
        const int cur = it & 1;
        // ---- prefetch next tile's K/V rows (global; overlaps everything) ----
        if (it < 7) {
            const size_t g = ((size_t)b * SS + chunk * 512 + (it + 1) * 64 + w * 16 + lane15) * 64 + q8;
            kf0 = *reinterpret_cast<const float4*>(key + g);
            kf1 = *reinterpret_cast<const float4*>(key + g + 4);
            kf2 = *reinterpret_cast<const float4*>(key + g + 32);
            kf3 = *reinterpret_cast<const float4*>(key + g + 36);
            vf0 = *reinterpret_cast<const float4*>(value + g);
            vf1 = *reinterpret_cast<const float4*>(value + g + 4);
            vf2 = *reinterpret_cast<const float4*>(value + g + 32);
            vf3 = *reinterpret_cast<const float4*>(value + g + 36);
        }
        // ---- kv / kvs GEMM from buffer cur, swapped: A=v (m=z), B=k' (n=x) ----
#pragma unroll
        for (int kstep = 0; kstep < 2; ++kstep) {
            const int so = kstep * 32;
            short8 aV  = *reinterpret_cast<const short8*>(&vT [cur][(w * 16 + lane15) * 72 + so + q8]);
            short8 aVS = *reinterpret_cast<const short8*>(&vsT[cur][(w * 16 + lane15) * 72 + so + q8]);
#pragma unroll
            for (int nt = 0; nt < 4; ++nt) {
                short8 bK = *reinterpret_cast<const short8*>(&kT[cur][(nt * 16 + lane15) * 72 + so + q8]);
                ckv[nt]  = MFMA(aV,  bK, ckv[nt]);
                ckvs[nt] = MFMA(aVS, bK, ckvs[nt]);
            }
        }
        // ---- ksum / kssum partials (thread: x = l, s-range [w*16,+16)) ----
        {
            const int sbase = it * 64;
            short8 k0 = *reinterpret_cast<const short8*>(&kT[cur][l * 72 + w * 16]);
            short8 k1 = *reinterpret_cast<const short8*>(&kT[cur][l * 72 + w * 16 + 8]);
#pragma unroll
            for (int e = 0; e < 8; ++e) {
                float fa = bf2f(k0[e]), fb = bf2f(k1[e]);
                aks  += fa + fb;
                akss += fa * ssin[sbase + w * 16 + e] + fb * ssin[sbase + w * 16 + 8 + e];
            }
        }
        // ---- project tile it+1 into the other buffer (same interval) ----
        if (it < 7) proj_store(cur ^ 1, (it + 1) * 64);
        __syncthreads();
    }

    // ---- commit: coalesced non-atomic partial stores ([z][x], x = lane15) ----
    const int bh = b * HH + h;
    const size_t pbase = ((size_t)(chunk * 64) + bh) * 4096;
#pragma unroll
    for (int nt = 0; nt < 4; ++nt) {
        const int x = nt * 16 + lane15;
#pragma unroll
        for (int r = 0; r < 4; ++r) {
            const int z = w * 16 + q4 + r;
            pkv [pbase + z * 64 + x] = ckv[nt][r];
            pkvs[pbase + z * 64 + x] = ckvs[nt][r];
        }
    }
    sred[t] = aks; sred[256 + t] = akss;
    __syncthreads();
    if (t < 64) {
        pks[((size_t)(chunk * 64) + bh) * 128 + t] =
            sred[t] + sred[64 + t] + sred[128 + t] + sred[192 + t];
    } else if (t < 128) {
        int tt = t - 64;
        pks[((size_t)(chunk * 64) + bh) * 128 + t] =
            sred[256 + tt] + sred[320 + tt] + sred[384 + tt] + sred[448 + tt];
    }
}

// ---------------------------------------------------------------------------
// Reduce 8 chunk partials -> bf16 kv/kvs + fp32 ksums.
__global__ __launch_bounds__(256) void k_reduce(
    const float* __restrict__ pkv, const float* __restrict__ pkvs,
    const float* __restrict__ pks,
    short* __restrict__ kvb, short* __restrict__ kvsb,
    float* __restrict__ ksums)
{
    const int blk = blockIdx.x, t = threadIdx.x;
    if (blk < 512) {
        const float* src = (blk < 256) ? pkv : pkvs;
        short* dst = (blk < 256) ? kvb : kvsb;
        const int o4 = (blk & 255) * 256 + t;          // float4 index, 0..65535
        float4 s = make_float4(0.f, 0.f, 0.f, 0.f);
#pragma unroll
        for (int c = 0; c < 8; ++c) {
            float4 v = reinterpret_cast<const float4*>(src + (size_t)c * 262144)[o4];
            s.x += v.x; s.y += v.y; s.z += v.z; s.w += v.w;
        }
        st4(dst + (size_t)o4 * 4, f2bf(s.x), f2bf(s.y), f2bf(s.z), f2bf(s.w));
    } else {
        const int g = (blk - 512) * 256 + t;           // float4 index, 0..2047
        float4 s = make_float4(0.f, 0.f, 0.f, 0.f);
#pragma unroll
        for (int c = 0; c < 8; ++c) {
            float4 v = reinterpret_cast<const float4*>(pks + (size_t)c * 8192)[g];
            s.x += v.x; s.y += v.y; s.z += v.z; s.w += v.w;
        }
        reinterpret_cast<float4*>(ksums)[g] = s;
    }
}

// ---------------------------------------------------------------------------
// Phase 2 (register-slimmed for true 4 blocks/CU): R5 geometry (grid 128x2x4,
// 2 heads/wave, atomicAdd combine) but the wave body is phase-pinned with
// sched_barrier(0) and rt-SEQUENTIAL in the numerator/dense (statically named
// cdA/cdB accumulators) so peak live regs fit the 128-total cap of (256,4)
// without scratch spill (the R4/R5 failure mode).
// Denominator ksums loads are chunked 2x16 terms to cap live float4s at 8.
#define RT_PASS(RT, CCSR, INVR, CD)                                                           \
    {                                                                                         \
        short8 qf0 = *reinterpret_cast<const short8*>(&sqp[((RT) * 16 + lane15) * 72 + q8]);  \
        short8 qf1 = *reinterpret_cast<const short8*>(&sqp[((RT) * 16 + lane15) * 72 + 32 + q8]); \
        f32x4 cv1[4], cv2[4];                                                                 \
        _Pragma("unroll")                                                                     \
        for (int nt = 0; nt < 4; ++nt) {                                                      \
            cv1[nt] = (f32x4){0.f, 0.f, 0.f, 0.f};                                            \
            cv2[nt] = (f32x4){0.f, 0.f, 0.f, 0.f};                                            \
        }                                                                                     \
        _Pragma("unroll")                                                                     \
        for (int nt = 0; nt < 4; ++nt) {                                                      \
            const short* a1 = kv1 + (nt * 16 + lane15) * 64;                                  \
            const short* a2 = kv2 + (nt * 16 + lane15) * 64;                                  \
            short8 f10 = *reinterpret_cast<const short8*>(a1 + q8);                           \
            short8 f11 = *reinterpret_cast<const short8*>(a1 + 32 + q8);                      \
            short8 f20 = *reinterpret_cast<const short8*>(a2 + q8);                           \
            short8 f21 = *reinterpret_cast<const short8*>(a2 + 32 + q8);                      \
            cv1[nt] = MFMA(f10, qf0, cv1[nt]);                                                \
            cv1[nt] = MFMA(f11, qf1, cv1[nt]);                                                \
            cv2[nt] = MFMA(f20, qf0, cv2[nt]);                                                \
            cv2[nt] = MFMA(f21, qf1, cv2[nt]);                                                \
        }                                                                                     \
        _Pragma("unroll")                                                                     \
        for (int nt = 0; nt < 4; ++nt) {                                                      \
            short e0 = f2bf((cv1[nt][0] + (CCSR) * cv2[nt][0]) * (INVR));                     \
            short e1 = f2bf((cv1[nt][1] + (CCSR) * cv2[nt][1]) * (INVR));                     \
            short e2 = f2bf((cv1[nt][2] + (CCSR) * cv2[nt][2]) * (INVR));                     \
            short e3 = f2bf((cv1[nt][3] + (CCSR) * cv2[nt][3]) * (INVR));                     \
            st4(&sOw[lane15 * 72 + nt * 16 + q4], e0, e1, e2, e3);                            \
        }                                                                                     \
        short8 of0 = *reinterpret_cast<const short8*>(&sOw[lane15 * 72 + q8]);                \
        short8 of1 = *reinterpret_cast<const short8*>(&sOw[lane15 * 72 + 32 + q8]);           \
        _Pragma("unroll")                                                                     \
        for (int nt = 0; nt < 4; ++nt) {                                                      \
            short8 wd0 = *reinterpret_cast<const short8*>(wdh + (nt * 16 + lane15) * 64 + q8);        \
            short8 wd1 = *reinterpret_cast<const short8*>(wdh + (nt * 16 + lane15) * 64 + 32 + q8);   \
            CD[nt] = MFMA(of0, wd0, CD[nt]);                                                  \
            CD[nt] = MFMA(of1, wd1, CD[nt]);                                                  \
        }                                                                                     \
    }

#define DTERM(qv, ka, kb) (bf2f(qv) * ((ka) + ccr * (kb)))

__global__ __launch_bounds__(256, 4) void k_phase2(
    const float* __restrict__ query, const float* __restrict__ wq_b,
    const short* __restrict__ wqTb,
    const short* __restrict__ kvb, const short* __restrict__ kvsb,
    const float* __restrict__ ksums,
    const short* __restrict__ wdTb, const float* __restrict__ dense_b,
    float* __restrict__ out)
{
    const int st = blockIdx.x, g = blockIdx.y, b = blockIdx.z;
    const int s0 = st * 32;
    const int t = threadIdx.x, w = t >> 6, l = t & 63;
    const int lane15 = l & 15, q8 = (l >> 4) * 8, q4 = (l >> 4) * 4;

    // LDS union: compute = sqin[32][72] | per-wave sqp[32][72] | per-wave sO[16][72]
    //            reduce view = per-wave float red[32][68]
    __shared__ __align__(16) char smem[34816];
    __shared__ float scc[32];
    short* sqin = reinterpret_cast<short*>(smem);                    // [32][72]
    short* sqp  = reinterpret_cast<short*>(smem) + 2304 * (1 + w);   // wave's q' [32][72]
    short* sOw  = reinterpret_cast<short*>(smem) + 2304 * 5 + 1152 * w;  // wave's O [16][72]

    // stage q tile (fp32 -> bf16, s-major): 256 thr x 8 floats = 32x64
    {
        const int row = t >> 3, c8 = (t & 7) * 8;
        const float* qp = query + ((size_t)b * SS + s0 + row) * 64 + c8;
        float4 f0 = *reinterpret_cast<const float4*>(qp);
        float4 f1 = *reinterpret_cast<const float4*>(qp + 4);
        *reinterpret_cast<short8*>(&sqin[row * 72 + c8]) = cvt8(f0, f1);
    }
    if (t < 32) {
        float p = PI_C * (float)(s0 + t) * (1.f / 4096.f);
        scc[t] = __cosf(p) + __sinf(p);
    }
    f32x4 cdA[4], cdB[4];
#pragma unroll
    for (int nt = 0; nt < 4; ++nt) {
        cdA[nt] = (f32x4){0.f, 0.f, 0.f, 0.f};
        cdB[nt] = (f32x4){0.f, 0.f, 0.f, 0.f};
    }
    __syncthreads();   // q tile + scc ready (only barrier before epilogue)

    const float ccs0 = scc[lane15], ccs1 = scc[16 + lane15];  // cos+sin for s-col
    const int drow = l >> 1, dxh = (l & 1) * 32;              // denominator row / x-half
    const float ccr = scc[drow];

#pragma unroll 1
    for (int i = 0; i < 2; ++i) {
        const int h = (g << 3) | (i << 2) | w;
        const size_t bh = (size_t)(b * HH + h);
        const short* wqh = wqTb + (size_t)h * 4096;
        const short* wdh = wdTb + (size_t)h * 4096;
        const short* kv1 = kvb  + bh * 4096;
        const short* kv2 = kvsb + bh * 4096;

        // ---- Q projection, SWAPPED (A=wq^T, B=q^T), rt-paired; aq scoped ----
        {
            short8 aq00 = *reinterpret_cast<const short8*>(&sqin[lane15 * 72 + q8]);
            short8 aq01 = *reinterpret_cast<const short8*>(&sqin[lane15 * 72 + 32 + q8]);
            short8 aq10 = *reinterpret_cast<const short8*>(&sqin[(16 + lane15) * 72 + q8]);
            short8 aq11 = *reinterpret_cast<const short8*>(&sqin[(16 + lane15) * 72 + 32 + q8]);
            f32x4 cq[2][4];
#pragma unroll
            for (int rt = 0; rt < 2; ++rt)
#pragma unroll
                for (int nt = 0; nt < 4; ++nt) cq[rt][nt] = (f32x4){0.f, 0.f, 0.f, 0.f};
#pragma unroll
            for (int nt = 0; nt < 4; ++nt) {
                short8 b0 = *reinterpret_cast<const short8*>(wqh + (nt * 16 + lane15) * 64 + q8);
                short8 b1 = *reinterpret_cast<const short8*>(wqh + (nt * 16 + lane15) * 64 + 32 + q8);
                cq[0][nt] = MFMA(b0, aq00, cq[0][nt]);
                cq[1][nt] = MFMA(b0, aq10, cq[1][nt]);
                cq[0][nt] = MFMA(b1, aq01, cq[0][nt]);
                cq[1][nt] = MFMA(b1, aq11, cq[1][nt]);
            }
            // bias + elu, store q' s-major
#pragma unroll
            for (int nt = 0; nt < 4; ++nt) {
                float4 bq = *reinterpret_cast<const float4*>(wq_b + h * 64 + nt * 16 + q4);
#pragma unroll
                for (int rt = 0; rt < 2; ++rt) {
                    short e0 = f2bf(elu1(cq[rt][nt][0] + bq.x));
                    short e1 = f2bf(elu1(cq[rt][nt][1] + bq.y));
                    short e2 = f2bf(elu1(cq[rt][nt][2] + bq.z));
                    short e3 = f2bf(elu1(cq[rt][nt][3] + bq.w));
                    st4(&sqp[(rt * 16 + lane15) * 72 + nt * 16 + q4], e0, e1, e2, e3);
                }
            }
        }
        __builtin_amdgcn_sched_barrier(0);   // q'-phase regs die here

        // ---- denominator: lane covers row drow, x-half dxh; 2 chunks of 16 ----
        float invs0, invs1;
        {
            const float* kp = ksums + bh * 128 + dxh;
            float dsum;
            {
                float4 A0 = *reinterpret_cast<const float4*>(kp);
                float4 A1 = *reinterpret_cast<const float4*>(kp + 4);
                float4 A2 = *reinterpret_cast<const float4*>(kp + 8);
                float4 A3 = *reinterpret_cast<const float4*>(kp + 12);
                float4 B0 = *reinterpret_cast<const float4*>(kp + 64);
                float4 B1 = *reinterpret_cast<const float4*>(kp + 68);
                float4 B2 = *reinterpret_cast<const float4*>(kp + 72);
                float4 B3 = *reinterpret_cast<const float4*>(kp + 76);
                short8 qa = *reinterpret_cast<const short8*>(&sqp[drow * 72 + dxh]);
                short8 qb = *reinterpret_cast<const short8*>(&sqp[drow * 72 + dxh + 8]);
                dsum = DTERM(qa[0], A0.x, B0.x) + DTERM(qa[1], A0.y, B0.y)
                     + DTERM(qa[2], A0.z, B0.z) + DTERM(qa[3], A0.w, B0.w)
                     + DTERM(qa[4], A1.x, B1.x) + DTERM(qa[5], A1.y, B1.y)
                     + DTERM(qa[6], A1.z, B1.z) + DTERM(qa[7], A1.w, B1.w)
                     + DTERM(qb[0], A2.x, B2.x) + DTERM(qb[1], A2.y, B2.y)
                     + DTERM(qb[2], A2.z, B2.z) + DTERM(qb[3], A2.w, B2.w)
                     + DTERM(qb[4], A3.x, B3.x) + DTERM(qb[5], A3.y, B3.y)
                     + DTERM(qb[6], A3.z, B3.z) + DTERM(qb[7], A3.w, B3.w);
            }
            __builtin_amdgcn_sched_barrier(0);   // chunk-0 float4s die here
            {
                float4 A4 = *reinterpret_cast<const float4*>(kp + 16);
                float4 A5 = *reinterpret_cast<const float4*>(kp + 20);
                float4 A6 = *reinterpret_cast<const float4*>(kp + 24);
                float4 A7 = *reinterpret_cast<const float4*>(kp + 28);
                float4 B4 = *reinterpret_cast<const float4*>(kp + 80);
                float4 B5 = *reinterpret_cast<const float4*>(kp + 84);
                float4 B6 = *reinterpret_cast<const float4*>(kp + 88);
                float4 B7 = *reinterpret_cast<const float4*>(kp + 92);
                short8 qc = *reinterpret_cast<const short8*>(&sqp[drow * 72 + dxh + 16]);
                short8 qd = *reinterpret_cast<const short8*>(&sqp[drow * 72 + dxh + 24]);
                dsum += DTERM(qc[0], A4.x, B4.x) + DTERM(qc[1], A4.y, B4.y)
                      + DTERM(qc[2], A4.z, B4.z) + DTERM(qc[3], A4.w, B4.w)
                      + DTERM(qc[4], A5.x, B5.x) + DTERM(qc[5], A5.y, B5.y)
                      + DTERM(qc[6], A5.z, B5.z) + DTERM(qc[7], A5.w, B5.w)
                      + DTERM(qd[0], A6.x, B6.x) + DTERM(qd[1], A6.y, B6.y)
                      + DTERM(qd[2], A6.z, B6.z) + DTERM(qd[3], A6.w, B6.w)
                      + DTERM(qd[4], A7.x, B7.x) + DTERM(qd[5], A7.y, B7.y)
                      + DTERM(qd[6], A7.z, B7.z) + DTERM(qd[7], A7.w, B7.w);
            }
            dsum += __shfl_xor(dsum, 1);
            float invd = 1.f / (dsum + 1e-5f);
            invs0 = __shfl(invd, lane15 * 2);
            invs1 = __shfl(invd, (16 + lane15) * 2);
        }
        __builtin_amdgcn_sched_barrier(0);   // denominator regs die here

        // ---- numerator + dense, rt-SEQUENTIAL (cv pressure halved) ----
        RT_PASS(0, ccs0, invs0, cdA)
        __builtin_amdgcn_sched_barrier(0);   // rt=0's cv1/cv2 die before rt=1
        RT_PASS(1, ccs1, invs1, cdB)
        __builtin_amdgcn_sched_barrier(0);
    }

    // ---- cross-wave reduction of dense partials (re-alias LDS union) ----
    __syncthreads();   // all compute reads of smem done
    {
        float* red = reinterpret_cast<float*>(smem) + 2176 * w;   // [32][68]
#pragma unroll
        for (int nt = 0; nt < 4; ++nt)
#pragma unroll
            for (int r = 0; r < 4; ++r) {
                red[(q4 + r) * 68 + nt * 16 + lane15]      = cdA[nt][r];
                red[(16 + q4 + r) * 68 + nt * 16 + lane15] = cdB[nt][r];
            }
    }
    __syncthreads();
    {
        const int row = t >> 3, c8 = (t & 7) * 8;
        float acc[8] = {0.f, 0.f, 0.f, 0.f, 0.f, 0.f, 0.f, 0.f};
#pragma unroll
        for (int ww = 0; ww < 4; ++ww) {
            const float* red = reinterpret_cast<const float*>(smem) + 2176 * ww;
            float4 v0 = *reinterpret_cast<const float4*>(red + row * 68 + c8);
            float4 v1 = *reinterpret_cast<const float4*>(red + row * 68 + c8 + 4);
            acc[0] += v0.x; acc[1] += v0.y; acc[2] += v0.z; acc[3] += v0.w;
            acc[4] += v1.x; acc[5] += v1.y; acc[6] += v1.z; acc[7] += v1.w;
        }
        if (g == 0) {
            float4 d0 = *reinterpret_cast<const float4*>(dense_b + c8);
            float4 d1 = *reinterpret_cast<const float4*>(dense_b + c8 + 4);
            acc[0] += d0.x; acc[1] += d0.y; acc[2] += d0.z; acc[3] += d0.w;
            acc[4] += d1.x; acc[5] += d1.y; acc[6] += d1.z; acc[7] += d1.w;
        }
        float* op = out + ((size_t)b * SS + s0 + row) * 64 + c8;
#pragma unroll
        for (int j = 0; j < 8; ++j) atomicAdd(op + j, acc[j]);
    }
}

// ---------------------------------------------------------------------------
extern "C" void kernel_launch(void* const* d_in, const int* in_sizes, int n_in,
                              void* d_out, int out_size, void* d_ws, size_t ws_size,
                              hipStream_t stream) {
    const float* query   = (const float*)d_in[0];
    const float* key     = (const float*)d_in[1];
    const float* value   = (const float*)d_in[2];
    // d_in[3] attn_mask unused
    const float* wq_w    = (const float*)d_in[4];
    const float* wq_b    = (const float*)d_in[5];
    const float* wk_w    = (const float*)d_in[6];
    const float* wk_b    = (const float*)d_in[7];
    const float* wv_w    = (const float*)d_in[8];
    const float* wv_b    = (const float*)d_in[9];
    const float* dense_w = (const float*)d_in[10];
    const float* dense_b = (const float*)d_in[11];
    float* out = (float*)d_out;

    char* ws = (char*)d_ws;
    float* pkv   = (float*)(ws);
    float* pkvs  = (float*)(ws + 8388608);
    float* pks   = (float*)(ws + 16777216);
    short* kvb   = (short*)(ws + 17039360);
    short* kvsb  = (short*)(ws + 17563648);
    float* ksums = (float*)(ws + 18087936);
    short* wT    = (short*)(ws + 18120704);  // wq|wk|wv|wd, 65536 shorts each
    short* wqTb  = wT;
    short* wkTb  = wT + 65536;
    short* wvTb  = wT + 131072;
    short* wdTb  = wT + 196608;

    // zero output for the 2-group atomicAdd combine (graph-capture safe)
    hipMemsetAsync(out, 0, (size_t)out_size, stream);

    hipLaunchKernelGGL(k_prep, dim3(16, 4), dim3(256), 0, stream,
                       wq_w, wk_w, wv_w, dense_w, wT);
    hipLaunchKernelGGL(k_phase1, dim3(8, HH, BB), dim3(256), 0, stream,
                       key, value, wk_b, wv_b, wkTb, wvTb, pkv, pkvs, pks);
    hipLaunchKernelGGL(k_reduce, dim3(520), dim3(256), 0, stream,
                       pkv, pkvs, pks, kvb, kvsb, ksums);
    hipLaunchKernelGGL(k_phase2, dim3(128, 2, BB), dim3(256), 0, stream,
                       query, wq_b, wqTb, kvb, kvsb, ksums, wdTb, dense_b, out);
}

// Round 7
// 200.250 us; speedup vs baseline: 1.1915x; 1.1915x over previous
//
#include <hip/hip_runtime.h>
#include <math.h>

// Problem constants
#define BB 4
#define SS 4096
#define DD 64
#define HH 16
#define PI_C 3.1415f

// ---------------------------------------------------------------------------
// ws layout (bytes):
//   0        : pkv   fp32 [8][64bh][z*64+x]   8,388,608
//   8388608  : pkvs  fp32 [8][64bh][z*64+x]   8,388,608
//   16777216 : pks   fp32 [8][64bh][128]        262,144   (ksum|kssum)
//   17039360 : kvb   bf16 [64bh][z*64+x]        524,288
//   17563648 : kvsb  bf16                       524,288
//   18087936 : ksums fp32 [64bh][128]            32,768
//   18120704 : wT    bf16 wq|wk|wv|wd x 65536   524,288
//   total ~18.6 MB
// ---------------------------------------------------------------------------

typedef __attribute__((ext_vector_type(8))) short short8;   // 8 x bf16 frag
typedef __attribute__((ext_vector_type(4))) float f32x4;    // MFMA C/D frag

#define MFMA(a, b, c) __builtin_amdgcn_mfma_f32_16x16x32_bf16(a, b, c, 0, 0, 0)

__device__ __forceinline__ short f2bf(float f) {
    union { float f; unsigned u; } v; v.f = f;
    unsigned r = v.u + 0x7FFFu + ((v.u >> 16) & 1u);   // round-to-nearest-even
    return (short)(r >> 16);
}
__device__ __forceinline__ float bf2f(short s) {
    union { unsigned u; float f; } v;
    v.u = ((unsigned)(unsigned short)s) << 16;
    return v.f;
}
__device__ __forceinline__ short8 cvt8(float4 a, float4 b) {
    short8 r;
    r[0] = f2bf(a.x); r[1] = f2bf(a.y); r[2] = f2bf(a.z); r[3] = f2bf(a.w);
    r[4] = f2bf(b.x); r[5] = f2bf(b.y); r[6] = f2bf(b.z); r[7] = f2bf(b.w);
    return r;
}
__device__ __forceinline__ float elu1(float x) { return x > 0.f ? x + 1.f : __expf(x); }
__device__ __forceinline__ void st4(short* p, short a, short b, short c, short d) {
    union { uint2 u; short s[4]; } x;
    x.s[0] = a; x.s[1] = b; x.s[2] = c; x.s[3] = d;
    *reinterpret_cast<uint2*>(p) = x.u;
}

// ---------------------------------------------------------------------------
// Transpose + bf16-convert weights: wq/wk/wv (64 x 1024) and dense_w (1024 x 64)
// into per-head [out_col][in_dim] layout so MFMA B-frags are contiguous 16B loads.
__global__ __launch_bounds__(256) void k_prep(
    const float* __restrict__ wq, const float* __restrict__ wk,
    const float* __restrict__ wv, const float* __restrict__ wd,
    short* __restrict__ dst)
{
    const int h = blockIdx.x, y = blockIdx.y, t = threadIdx.x;
    const float* src = (y == 0) ? wq : (y == 1) ? wk : (y == 2) ? wv : wd;
    const int rs = (y < 3) ? 1024 : 64;
    const size_t srcbase = (y < 3) ? (size_t)(h * 64) : (size_t)(h * 4096);
    short* dm = dst + (size_t)y * 65536 + (size_t)h * 4096;
#pragma unroll
    for (int j = 0; j < 4; ++j) {
        int idx = j * 1024 + t * 4;
        int r = idx >> 6, c = idx & 63;
        float4 v = *reinterpret_cast<const float4*>(src + (size_t)r * rs + srcbase + c);
        dm[(c + 0) * 64 + r] = f2bf(v.x);
        dm[(c + 1) * 64 + r] = f2bf(v.y);
        dm[(c + 2) * 64 + r] = f2bf(v.z);
        dm[(c + 3) * 64 + r] = f2bf(v.w);
    }
}

// ---------------------------------------------------------------------------
// Phase 1 (R2-exact, measured-good): project K,V (MFMA) -> transposed bf16
// tiles in DOUBLE-BUFFERED LDS so projection of tile t+1 and the kv GEMM of
// tile t share one barrier interval. kv/kvs GEMM uses SWAPPED operands
// (A=v, B=k') so C-layout is [z][x] -> coalesced non-atomic partial stores.
__global__ __launch_bounds__(256, 2) void k_phase1(
    const float* __restrict__ key, const float* __restrict__ value,
    const float* __restrict__ wk_b, const float* __restrict__ wv_b,
    const short* __restrict__ wkTb, const short* __restrict__ wvTb,
    float* __restrict__ pkv, float* __restrict__ pkvs,
    float* __restrict__ pks)
{
    const int chunk = blockIdx.x, h = blockIdx.y, b = blockIdx.z;
    const int t = threadIdx.x, w = t >> 6, l = t & 63;
    const int lane15 = l & 15, q8 = (l >> 4) * 8, q4 = (l >> 4) * 4;

    __shared__ short kT[2][64 * 72], vT[2][64 * 72], vsT[2][64 * 72];   // [buf][x|z][s]
    __shared__ float ssin[512];
    __shared__ float sbk[64], sbv[64];
    __shared__ float sred[512];

    // projection weight B-frags -> registers (once per block, L2-hot)
    short8 bkf[2][4], bvf[2][4];
    {
        const short* wkh = wkTb + (size_t)h * 4096;
        const short* wvh = wvTb + (size_t)h * 4096;
#pragma unroll
        for (int kss = 0; kss < 2; ++kss)
#pragma unroll
            for (int nt = 0; nt < 4; ++nt) {
                bkf[kss][nt] = *reinterpret_cast<const short8*>(wkh + (nt * 16 + lane15) * 64 + kss * 32 + q8);
                bvf[kss][nt] = *reinterpret_cast<const short8*>(wvh + (nt * 16 + lane15) * 64 + kss * 32 + q8);
            }
    }
    ssin[t]       = __sinf(PI_C * (float)(chunk * 512 + t)       * (1.f / 4096.f));
    ssin[t + 256] = __sinf(PI_C * (float)(chunk * 512 + t + 256) * (1.f / 4096.f));
    if (t < 64) sbk[t] = wk_b[h * 64 + t];
    else if (t < 128) sbv[t - 64] = wv_b[h * 64 + (t - 64)];

    // prefetch K/V rows for iter 0
    float4 kf0, kf1, kf2, kf3, vf0, vf1, vf2, vf3;
    {
        const size_t g = ((size_t)b * SS + chunk * 512 + w * 16 + lane15) * 64 + q8;
        kf0 = *reinterpret_cast<const float4*>(key + g);
        kf1 = *reinterpret_cast<const float4*>(key + g + 4);
        kf2 = *reinterpret_cast<const float4*>(key + g + 32);
        kf3 = *reinterpret_cast<const float4*>(key + g + 36);
        vf0 = *reinterpret_cast<const float4*>(value + g);
        vf1 = *reinterpret_cast<const float4*>(value + g + 4);
        vf2 = *reinterpret_cast<const float4*>(value + g + 32);
        vf3 = *reinterpret_cast<const float4*>(value + g + 36);
    }

    f32x4 ckv[4], ckvs[4];
#pragma unroll
    for (int i = 0; i < 4; ++i) {
        ckv[i]  = (f32x4){0.f, 0.f, 0.f, 0.f};
        ckvs[i] = (f32x4){0.f, 0.f, 0.f, 0.f};
    }
    float aks = 0.f, akss = 0.f;

    // projection + bias + act + transposed bf16 stores into buffer `buf`
    auto proj_store = [&](int buf, int sbase) {
        f32x4 ckp[4], cvp[4];
#pragma unroll
        for (int i = 0; i < 4; ++i) {
            ckp[i] = (f32x4){0.f, 0.f, 0.f, 0.f};
            cvp[i] = (f32x4){0.f, 0.f, 0.f, 0.f};
        }
        short8 ak0 = cvt8(kf0, kf1), ak1 = cvt8(kf2, kf3);
        short8 av0 = cvt8(vf0, vf1), av1 = cvt8(vf2, vf3);
#pragma unroll
        for (int nt = 0; nt < 4; ++nt) {
            ckp[nt] = MFMA(ak0, bkf[0][nt], ckp[nt]);
            cvp[nt] = MFMA(av0, bvf[0][nt], cvp[nt]);
            ckp[nt] = MFMA(ak1, bkf[1][nt], ckp[nt]);
            cvp[nt] = MFMA(av1, bvf[1][nt], cvp[nt]);
        }
        const int srel = w * 16 + q4;
#pragma unroll
        for (int nt = 0; nt < 4; ++nt) {
            const int x = nt * 16 + lane15;
            const float bk = sbk[x], bv = sbv[x];
            short ek[4], ev[4], es[4];
#pragma unroll
            for (int r = 0; r < 4; ++r) {
                float kk = elu1(ckp[nt][r] + bk);
                float vv = cvp[nt][r] + bv;
                ek[r] = f2bf(kk);
                ev[r] = f2bf(vv);
                es[r] = f2bf(vv * ssin[sbase + srel + r]);
            }
            st4(&kT [buf][x * 72 + srel], ek[0], ek[1], ek[2], ek[3]);
            st4(&vT [buf][x * 72 + srel], ev[0], ev[1], ev[2], ev[3]);
            st4(&vsT[buf][x * 72 + srel], es[0], es[1], es[2], es[3]);
        }
    };

    __syncthreads();           // ssin/sbk/sbv visible
    proj_store(0, 0);          // peeled: tile 0 -> buffer 0
    __syncthreads();           // buffer 0 complete

#pragma unroll 1
    for (int it = 0; it < 8; ++it) {
        const int cur = it & 1;
        // ---- prefetch next tile's K/V rows (global; overlaps everything) ----
        if (it < 7) {
            const size_t g = ((size_t)b * SS + chunk * 512 + (it + 1) * 64 + w * 16 + lane15) * 64 + q8;
            kf0 = *reinterpret_cast<const float4*>(key + g);
            kf1 = *reinterpret_cast<const float4*>(key + g + 4);
            kf2 = *reinterpret_cast<const float4*>(key + g + 32);
            kf3 = *reinterpret_cast<const float4*>(key + g + 36);
            vf0 = *reinterpret_cast<const float4*>(value + g);
            vf1 = *reinterpret_cast<const float4*>(value + g + 4);
            vf2 = *reinterpret_cast<const float4*>(value + g + 32);
            vf3 = *reinterpret_cast<const float4*>(value + g + 36);
        }
        // ---- kv / kvs GEMM from buffer cur, swapped: A=v (m=z), B=k' (n=x) ----
#pragma unroll
        for (int kstep = 0; kstep < 2; ++kstep) {
            const int so = kstep * 32;
            short8 aV  = *reinterpret_cast<const short8*>(&vT [cur][(w * 16 + lane15) * 72 + so + q8]);
            short8 aVS = *reinterpret_cast<const short8*>(&vsT[cur][(w * 16 + lane15) * 72 + so + q8]);
#pragma unroll
            for (int nt = 0; nt < 4; ++nt) {
                short8 bK = *reinterpret_cast<const short8*>(&kT[cur][(nt * 16 + lane15) * 72 + so + q8]);
                ckv[nt]  = MFMA(aV,  bK, ckv[nt]);
                ckvs[nt] = MFMA(aVS, bK, ckvs[nt]);
            }
        }
        // ---- ksum / kssum partials (thread: x = l, s-range [w*16,+16)) ----
        {
            const int sbase = it * 64;
            short8 k0 = *reinterpret_cast<const short8*>(&kT[cur][l * 72 + w * 16]);
            short8 k1 = *reinterpret_cast<const short8*>(&kT[cur][l * 72 + w * 16 + 8]);
#pragma unroll
            for (int e = 0; e < 8; ++e) {
                float fa = bf2f(k0[e]), fb = bf2f(k1[e]);
                aks  += fa + fb;
                akss += fa * ssin[sbase + w * 16 + e] + fb * ssin[sbase + w * 16 + 8 + e];
            }
        }
        // ---- project tile it+1 into the other buffer (same interval) ----
        if (it < 7) proj_store(cur ^ 1, (it + 1) * 64);
        __syncthreads();
    }

    // ---- commit: coalesced non-atomic partial stores ([z][x], x = lane15) ----
    const int bh = b * HH + h;
    const size_t pbase = ((size_t)(chunk * 64) + bh) * 4096;
#pragma unroll
    for (int nt = 0; nt < 4; ++nt) {
        const int x = nt * 16 + lane15;
#pragma unroll
        for (int r = 0; r < 4; ++r) {
            const int z = w * 16 + q4 + r;
            pkv [pbase + z * 64 + x] = ckv[nt][r];
            pkvs[pbase + z * 64 + x] = ckvs[nt][r];
        }
    }
    sred[t] = aks; sred[256 + t] = akss;
    __syncthreads();
    if (t < 64) {
        pks[((size_t)(chunk * 64) + bh) * 128 + t] =
            sred[t] + sred[64 + t] + sred[128 + t] + sred[192 + t];
    } else if (t < 128) {
        int tt = t - 64;
        pks[((size_t)(chunk * 64) + bh) * 128 + t] =
            sred[256 + tt] + sred[320 + tt] + sred[384 + tt] + sred[448 + tt];
    }
}

// ---------------------------------------------------------------------------
// Reduce 8 chunk partials -> bf16 kv/kvs + fp32 ksums.
__global__ __launch_bounds__(256) void k_reduce(
    const float* __restrict__ pkv, const float* __restrict__ pkvs,
    const float* __restrict__ pks,
    short* __restrict__ kvb, short* __restrict__ kvsb,
    float* __restrict__ ksums)
{
    const int blk = blockIdx.x, t = threadIdx.x;
    if (blk < 512) {
        const float* src = (blk < 256) ? pkv : pkvs;
        short* dst = (blk < 256) ? kvb : kvsb;
        const int o4 = (blk & 255) * 256 + t;          // float4 index, 0..65535
        float4 s = make_float4(0.f, 0.f, 0.f, 0.f);
#pragma unroll
        for (int c = 0; c < 8; ++c) {
            float4 v = reinterpret_cast<const float4*>(src + (size_t)c * 262144)[o4];
            s.x += v.x; s.y += v.y; s.z += v.z; s.w += v.w;
        }
        st4(dst + (size_t)o4 * 4, f2bf(s.x), f2bf(s.y), f2bf(s.z), f2bf(s.w));
    } else {
        const int g = (blk - 512) * 256 + t;           // float4 index, 0..2047
        float4 s = make_float4(0.f, 0.f, 0.f, 0.f);
#pragma unroll
        for (int c = 0; c < 8; ++c) {
            float4 v = reinterpret_cast<const float4*>(pks + (size_t)c * 8192)[g];
            s.x += v.x; s.y += v.y; s.z += v.z; s.w += v.w;
        }
        reinterpret_cast<float4*>(ksums)[g] = s;
    }
}

// ---------------------------------------------------------------------------
// Phase 2: R2 body VERBATIM (96-reg regime, launch_bounds (256,2) -> NO reg
// cap, no spill) with ONE change: the 16 heads are split into 2 groups of 8
// across blockIdx.y -> grid 1024 blocks. Occupancy becomes min(grid 4, LDS 4,
// regs ~3) blocks/CU instead of grid-limited 2. Per-group dense partials are
// combined into the zeroed output via fp32 atomicAdd (bit-exact for 2 addends,
// verified R5/R6); group 0 adds dense_b.
__global__ __launch_bounds__(256, 2) void k_phase2(
    const float* __restrict__ query, const float* __restrict__ wq_b,
    const short* __restrict__ wqTb,
    const short* __restrict__ kvb, const short* __restrict__ kvsb,
    const float* __restrict__ ksums,
    const short* __restrict__ wdTb, const float* __restrict__ dense_b,
    float* __restrict__ out)
{
    const int st = blockIdx.x, g = blockIdx.y, b = blockIdx.z;
    const int s0 = st * 32;
    const int t = threadIdx.x, w = t >> 6, l = t & 63;
    const int lane15 = l & 15, q8 = (l >> 4) * 8, q4 = (l >> 4) * 4;

    // LDS union: compute = sqin[32][72] | per-wave sqp[32][72] | per-wave sO[16][72]
    //            reduce view = per-wave float red[32][68]
    __shared__ __align__(16) char smem[34816];
    __shared__ float scc[32];
    short* sqin = reinterpret_cast<short*>(smem);                    // [32][72]
    short* sqp  = reinterpret_cast<short*>(smem) + 2304 * (1 + w);   // wave's q' [32][72]
    short* sOw  = reinterpret_cast<short*>(smem) + 2304 * 5 + 1152 * w;  // wave's O [16][72]

    // stage q tile (fp32 -> bf16, s-major): 256 thr x 8 floats = 32x64
    {
        const int row = t >> 3, c8 = (t & 7) * 8;
        const float* qp = query + ((size_t)b * SS + s0 + row) * 64 + c8;
        float4 f0 = *reinterpret_cast<const float4*>(qp);
        float4 f1 = *reinterpret_cast<const float4*>(qp + 4);
        *reinterpret_cast<short8*>(&sqin[row * 72 + c8]) = cvt8(f0, f1);
    }
    if (t < 32) {
        float p = PI_C * (float)(s0 + t) * (1.f / 4096.f);
        scc[t] = __cosf(p) + __sinf(p);
    }
    f32x4 cd[2][4];
#pragma unroll
    for (int rt = 0; rt < 2; ++rt)
#pragma unroll
        for (int nt = 0; nt < 4; ++nt) cd[rt][nt] = (f32x4){0.f, 0.f, 0.f, 0.f};
    __syncthreads();   // q tile + scc ready (only barrier before epilogue)

    // hoisted head-independent values
    short8 aq[2][2];   // q^T B-frags for the 2 row-tiles
#pragma unroll
    for (int rt = 0; rt < 2; ++rt)
#pragma unroll
        for (int kss = 0; kss < 2; ++kss)
            aq[rt][kss] = *reinterpret_cast<const short8*>(&sqin[(rt * 16 + lane15) * 72 + kss * 32 + q8]);
    const float ccs0 = scc[lane15], ccs1 = scc[16 + lane15];  // cos+sin for s-col
    const int drow = l >> 1, dxh = (l & 1) * 32;              // denominator row / x-half
    const float ccr = scc[drow];

#pragma unroll 1
    for (int i = 0; i < 2; ++i) {
        const int h = (g << 3) | (i << 2) | w;
        const size_t bh = (size_t)(b * HH + h);
        const short* wqh = wqTb + (size_t)h * 4096;
        const short* wdh = wdTb + (size_t)h * 4096;
        const short* kv1 = kvb  + bh * 4096;
        const short* kv2 = kvsb + bh * 4096;

        // ---- Q projection, SWAPPED (A=wq^T, B=q^T): lane x=nt*16+q4+r, s=rt*16+lane15 ----
        f32x4 cq[2][4];
#pragma unroll
        for (int rt = 0; rt < 2; ++rt)
#pragma unroll
            for (int nt = 0; nt < 4; ++nt) cq[rt][nt] = (f32x4){0.f, 0.f, 0.f, 0.f};
#pragma unroll
        for (int nt = 0; nt < 4; ++nt) {
            short8 b0 = *reinterpret_cast<const short8*>(wqh + (nt * 16 + lane15) * 64 + q8);
            short8 b1 = *reinterpret_cast<const short8*>(wqh + (nt * 16 + lane15) * 64 + 32 + q8);
            cq[0][nt] = MFMA(b0, aq[0][0], cq[0][nt]);
            cq[1][nt] = MFMA(b0, aq[1][0], cq[1][nt]);
            cq[0][nt] = MFMA(b1, aq[0][1], cq[0][nt]);
            cq[1][nt] = MFMA(b1, aq[1][1], cq[1][nt]);
        }
        // bias + elu, store q' s-major
#pragma unroll
        for (int nt = 0; nt < 4; ++nt) {
            float4 bq = *reinterpret_cast<const float4*>(wq_b + h * 64 + nt * 16 + q4);
#pragma unroll
            for (int rt = 0; rt < 2; ++rt) {
                short e0 = f2bf(elu1(cq[rt][nt][0] + bq.x));
                short e1 = f2bf(elu1(cq[rt][nt][1] + bq.y));
                short e2 = f2bf(elu1(cq[rt][nt][2] + bq.z));
                short e3 = f2bf(elu1(cq[rt][nt][3] + bq.w));
                st4(&sqp[(rt * 16 + lane15) * 72 + nt * 16 + q4], e0, e1, e2, e3);
            }
        }

        // ---- denominator: lane covers row drow, x-half dxh (32 terms) ----
        float invs0, invs1;
        {
            const float* kp = ksums + bh * 128 + dxh;
            float4 A[8], Bv[8];
#pragma unroll
            for (int j = 0; j < 8; ++j) {
                A[j]  = *reinterpret_cast<const float4*>(kp + j * 4);
                Bv[j] = *reinterpret_cast<const float4*>(kp + 64 + j * 4);
            }
            short8 qr[4];
#pragma unroll
            for (int e = 0; e < 4; ++e)
                qr[e] = *reinterpret_cast<const short8*>(&sqp[drow * 72 + dxh + e * 8]);
            float dsum = 0.f;
#pragma unroll
            for (int j4 = 0; j4 < 8; ++j4)
#pragma unroll
                for (int e4 = 0; e4 < 4; ++e4)
                    dsum += bf2f(qr[j4 >> 1][(j4 & 1) * 4 + e4]) * (A[j4][e4] + ccr * Bv[j4][e4]);
            dsum += __shfl_xor(dsum, 1);
            float invd = 1.f / (dsum + 1e-5f);
            invs0 = __shfl(invd, lane15 * 2);
            invs1 = __shfl(invd, (16 + lane15) * 2);
        }

        // ---- numerator, SWAPPED (A=kv^T, B=q'^T): lane z=nt*16+q4+r, s=rt*16+lane15 ----
        short8 qf[2][2];
#pragma unroll
        for (int rt = 0; rt < 2; ++rt)
#pragma unroll
            for (int kss = 0; kss < 2; ++kss)
                qf[rt][kss] = *reinterpret_cast<const short8*>(&sqp[(rt * 16 + lane15) * 72 + kss * 32 + q8]);
        f32x4 cv1[2][4], cv2[2][4];
#pragma unroll
        for (int rt = 0; rt < 2; ++rt)
#pragma unroll
            for (int nt = 0; nt < 4; ++nt) {
                cv1[rt][nt] = (f32x4){0.f, 0.f, 0.f, 0.f};
                cv2[rt][nt] = (f32x4){0.f, 0.f, 0.f, 0.f};
            }
#pragma unroll
        for (int nt = 0; nt < 4; ++nt) {
            const short* a1 = kv1 + (nt * 16 + lane15) * 64;
            const short* a2 = kv2 + (nt * 16 + lane15) * 64;
            short8 f10 = *reinterpret_cast<const short8*>(a1 + q8);
            short8 f11 = *reinterpret_cast<const short8*>(a1 + 32 + q8);
            short8 f20 = *reinterpret_cast<const short8*>(a2 + q8);
            short8 f21 = *reinterpret_cast<const short8*>(a2 + 32 + q8);
#pragma unroll
            for (int rt = 0; rt < 2; ++rt) {
                cv1[rt][nt] = MFMA(f10, qf[rt][0], cv1[rt][nt]);
                cv1[rt][nt] = MFMA(f11, qf[rt][1], cv1[rt][nt]);
                cv2[rt][nt] = MFMA(f20, qf[rt][0], cv2[rt][nt]);
                cv2[rt][nt] = MFMA(f21, qf[rt][1], cv2[rt][nt]);
            }
        }
        // dense B-frags (reused across both row-tiles)
        short8 wdf[4][2];
#pragma unroll
        for (int nt = 0; nt < 4; ++nt)
#pragma unroll
            for (int kss = 0; kss < 2; ++kss)
                wdf[nt][kss] = *reinterpret_cast<const short8*>(wdh + (nt * 16 + lane15) * 64 + kss * 32 + q8);

        // ---- per row-tile: combine -> O scratch -> dense GEMM ----
#pragma unroll
        for (int rt = 0; rt < 2; ++rt) {
            const float ccsr = rt ? ccs1 : ccs0;
            const float invr = rt ? invs1 : invs0;
#pragma unroll
            for (int nt = 0; nt < 4; ++nt) {
                short e0 = f2bf((cv1[rt][nt][0] + ccsr * cv2[rt][nt][0]) * invr);
                short e1 = f2bf((cv1[rt][nt][1] + ccsr * cv2[rt][nt][1]) * invr);
                short e2 = f2bf((cv1[rt][nt][2] + ccsr * cv2[rt][nt][2]) * invr);
                short e3 = f2bf((cv1[rt][nt][3] + ccsr * cv2[rt][nt][3]) * invr);
                st4(&sOw[lane15 * 72 + nt * 16 + q4], e0, e1, e2, e3);
            }
            short8 of0 = *reinterpret_cast<const short8*>(&sOw[lane15 * 72 + q8]);
            short8 of1 = *reinterpret_cast<const short8*>(&sOw[lane15 * 72 + 32 + q8]);
#pragma unroll
            for (int nt = 0; nt < 4; ++nt) {
                cd[rt][nt] = MFMA(of0, wdf[nt][0], cd[rt][nt]);
                cd[rt][nt] = MFMA(of1, wdf[nt][1], cd[rt][nt]);
            }
        }
    }

    // ---- cross-wave reduction of dense partials (re-alias LDS union) ----
    __syncthreads();   // all compute reads of smem done
    {
        float* red = reinterpret_cast<float*>(smem) + 2176 * w;   // [32][68]
#pragma unroll
        for (int rt = 0; rt < 2; ++rt)
#pragma unroll
            for (int nt = 0; nt < 4; ++nt)
#pragma unroll
                for (int r = 0; r < 4; ++r)
                    red[(rt * 16 + q4 + r) * 68 + nt * 16 + lane15] = cd[rt][nt][r];
    }
    __syncthreads();
    {
        const int row = t >> 3, c8 = (t & 7) * 8;
        float acc[8] = {0.f, 0.f, 0.f, 0.f, 0.f, 0.f, 0.f, 0.f};
#pragma unroll
        for (int ww = 0; ww < 4; ++ww) {
            const float* red = reinterpret_cast<const float*>(smem) + 2176 * ww;
            float4 v0 = *reinterpret_cast<const float4*>(red + row * 68 + c8);
            float4 v1 = *reinterpret_cast<const float4*>(red + row * 68 + c8 + 4);
            acc[0] += v0.x; acc[1] += v0.y; acc[2] += v0.z; acc[3] += v0.w;
            acc[4] += v1.x; acc[5] += v1.y; acc[6] += v1.z; acc[7] += v1.w;
        }
        if (g == 0) {
            float4 d0 = *reinterpret_cast<const float4*>(dense_b + c8);
            float4 d1 = *reinterpret_cast<const float4*>(dense_b + c8 + 4);
            acc[0] += d0.x; acc[1] += d0.y; acc[2] += d0.z; acc[3] += d0.w;
            acc[4] += d1.x; acc[5] += d1.y; acc[6] += d1.z; acc[7] += d1.w;
        }
        float* op = out + ((size_t)b * SS + s0 + row) * 64 + c8;
#pragma unroll
        for (int j = 0; j < 8; ++j) atomicAdd(op + j, acc[j]);
    }
}

// ---------------------------------------------------------------------------
extern "C" void kernel_launch(void* const* d_in, const int* in_sizes, int n_in,
                              void* d_out, int out_size, void* d_ws, size_t ws_size,
                              hipStream_t stream) {
    const float* query   = (const float*)d_in[0];
    const float* key     = (const float*)d_in[1];
    const float* value   = (const float*)d_in[2];
    // d_in[3] attn_mask unused
    const float* wq_w    = (const float*)d_in[4];
    const float* wq_b    = (const float*)d_in[5];
    const float* wk_w    = (const float*)d_in[6];
    const float* wk_b    = (const float*)d_in[7];
    const float* wv_w    = (const float*)d_in[8];
    const float* wv_b    = (const float*)d_in[9];
    const float* dense_w = (const float*)d_in[10];
    const float* dense_b = (const float*)d_in[11];
    float* out = (float*)d_out;

    char* ws = (char*)d_ws;
    float* pkv   = (float*)(ws);
    float* pkvs  = (float*)(ws + 8388608);
    float* pks   = (float*)(ws + 16777216);
    short* kvb   = (short*)(ws + 17039360);
    short* kvsb  = (short*)(ws + 17563648);
    float* ksums = (float*)(ws + 18087936);
    short* wT    = (short*)(ws + 18120704);  // wq|wk|wv|wd, 65536 shorts each
    short* wqTb  = wT;
    short* wkTb  = wT + 65536;
    short* wvTb  = wT + 131072;
    short* wdTb  = wT + 196608;

    // zero output for the 2-group atomicAdd combine (graph-capture safe)
    hipMemsetAsync(out, 0, (size_t)out_size, stream);

    hipLaunchKernelGGL(k_prep, dim3(16, 4), dim3(256), 0, stream,
                       wq_w, wk_w, wv_w, dense_w, wT);
    hipLaunchKernelGGL(k_phase1, dim3(8, HH, BB), dim3(256), 0, stream,
                       key, value, wk_b, wv_b, wkTb, wvTb, pkv, pkvs, pks);
    hipLaunchKernelGGL(k_reduce, dim3(520), dim3(256), 0, stream,
                       pkv, pkvs, pks, kvb, kvsb, ksums);
    hipLaunchKernelGGL(k_phase2, dim3(128, 2, BB), dim3(256), 0, stream,
                       query, wq_b, wqTb, kvb, kvsb, ksums, wdTb, dense_b, out);
}

// Round 8
// 159.923 us; speedup vs baseline: 1.4920x; 1.2522x over previous
//
#include <hip/hip_runtime.h>
#include <math.h>

// Problem constants
#define BB 4
#define SS 4096
#define DD 64
#define HH 16
#define PI_C 3.1415f

// ---------------------------------------------------------------------------
// ws layout (bytes):
//   0        : pkv   fp32 [8][64bh][z*64+x]   8,388,608   (REUSED by phase2 as
//                                                          pout[2][4][4096][64])
//   8388608  : pkvs  fp32 [8][64bh][z*64+x]   8,388,608
//   16777216 : pks   fp32 [8][64bh][128]        262,144   (ksum|kssum)
//   17039360 : kvb   bf16 [64bh][z*64+x]        524,288
//   17563648 : kvsb  bf16                       524,288
//   18087936 : ksums fp32 [64bh][128]            32,768
//   18120704 : wT    bf16 wq|wk|wv|wd x 65536   524,288
//   total ~18.6 MB
// ---------------------------------------------------------------------------

typedef __attribute__((ext_vector_type(8))) short short8;   // 8 x bf16 frag
typedef __attribute__((ext_vector_type(4))) float f32x4;    // MFMA C/D frag

#define MFMA(a, b, c) __builtin_amdgcn_mfma_f32_16x16x32_bf16(a, b, c, 0, 0, 0)

__device__ __forceinline__ short f2bf(float f) {
    union { float f; unsigned u; } v; v.f = f;
    unsigned r = v.u + 0x7FFFu + ((v.u >> 16) & 1u);   // round-to-nearest-even
    return (short)(r >> 16);
}
__device__ __forceinline__ float bf2f(short s) {
    union { unsigned u; float f; } v;
    v.u = ((unsigned)(unsigned short)s) << 16;
    return v.f;
}
__device__ __forceinline__ short8 cvt8(float4 a, float4 b) {
    short8 r;
    r[0] = f2bf(a.x); r[1] = f2bf(a.y); r[2] = f2bf(a.z); r[3] = f2bf(a.w);
    r[4] = f2bf(b.x); r[5] = f2bf(b.y); r[6] = f2bf(b.z); r[7] = f2bf(b.w);
    return r;
}
__device__ __forceinline__ float elu1(float x) { return x > 0.f ? x + 1.f : __expf(x); }
__device__ __forceinline__ void st4(short* p, short a, short b, short c, short d) {
    union { uint2 u; short s[4]; } x;
    x.s[0] = a; x.s[1] = b; x.s[2] = c; x.s[3] = d;
    *reinterpret_cast<uint2*>(p) = x.u;
}

// ---------------------------------------------------------------------------
// Transpose + bf16-convert weights: wq/wk/wv (64 x 1024) and dense_w (1024 x 64)
// into per-head [out_col][in_dim] layout so MFMA B-frags are contiguous 16B loads.
__global__ __launch_bounds__(256) void k_prep(
    const float* __restrict__ wq, const float* __restrict__ wk,
    const float* __restrict__ wv, const float* __restrict__ wd,
    short* __restrict__ dst)
{
    const int h = blockIdx.x, y = blockIdx.y, t = threadIdx.x;
    const float* src = (y == 0) ? wq : (y == 1) ? wk : (y == 2) ? wv : wd;
    const int rs = (y < 3) ? 1024 : 64;
    const size_t srcbase = (y < 3) ? (size_t)(h * 64) : (size_t)(h * 4096);
    short* dm = dst + (size_t)y * 65536 + (size_t)h * 4096;
#pragma unroll
    for (int j = 0; j < 4; ++j) {
        int idx = j * 1024 + t * 4;
        int r = idx >> 6, c = idx & 63;
        float4 v = *reinterpret_cast<const float4*>(src + (size_t)r * rs + srcbase + c);
        dm[(c + 0) * 64 + r] = f2bf(v.x);
        dm[(c + 1) * 64 + r] = f2bf(v.y);
        dm[(c + 2) * 64 + r] = f2bf(v.z);
        dm[(c + 3) * 64 + r] = f2bf(v.w);
    }
}

// ---------------------------------------------------------------------------
// Phase 1 (R2-exact, measured-good): project K,V (MFMA) -> transposed bf16
// tiles in DOUBLE-BUFFERED LDS so projection of tile t+1 and the kv GEMM of
// tile t share one barrier interval. kv/kvs GEMM uses SWAPPED operands
// (A=v, B=k') so C-layout is [z][x] -> coalesced non-atomic partial stores.
__global__ __launch_bounds__(256, 2) void k_phase1(
    const float* __restrict__ key, const float* __restrict__ value,
    const float* __restrict__ wk_b, const float* __restrict__ wv_b,
    const short* __restrict__ wkTb, const short* __restrict__ wvTb,
    float* __restrict__ pkv, float* __restrict__ pkvs,
    float* __restrict__ pks)
{
    const int chunk = blockIdx.x, h = blockIdx.y, b = blockIdx.z;
    const int t = threadIdx.x, w = t >> 6, l = t & 63;
    const int lane15 = l & 15, q8 = (l >> 4) * 8, q4 = (l >> 4) * 4;

    __shared__ short kT[2][64 * 72], vT[2][64 * 72], vsT[2][64 * 72];   // [buf][x|z][s]
    __shared__ float ssin[512];
    __shared__ float sbk[64], sbv[64];
    __shared__ float sred[512];

    // projection weight B-frags -> registers (once per block, L2-hot)
    short8 bkf[2][4], bvf[2][4];
    {
        const short* wkh = wkTb + (size_t)h * 4096;
        const short* wvh = wvTb + (size_t)h * 4096;
#pragma unroll
        for (int kss = 0; kss < 2; ++kss)
#pragma unroll
            for (int nt = 0; nt < 4; ++nt) {
                bkf[kss][nt] = *reinterpret_cast<const short8*>(wkh + (nt * 16 + lane15) * 64 + kss * 32 + q8);
                bvf[kss][nt] = *reinterpret_cast<const short8*>(wvh + (nt * 16 + lane15) * 64 + kss * 32 + q8);
            }
    }
    ssin[t]       = __sinf(PI_C * (float)(chunk * 512 + t)       * (1.f / 4096.f));
    ssin[t + 256] = __sinf(PI_C * (float)(chunk * 512 + t + 256) * (1.f / 4096.f));
    if (t < 64) sbk[t] = wk_b[h * 64 + t];
    else if (t < 128) sbv[t - 64] = wv_b[h * 64 + (t - 64)];

    // prefetch K/V rows for iter 0
    float4 kf0, kf1, kf2, kf3, vf0, vf1, vf2, vf3;
    {
        const size_t g = ((size_t)b * SS + chunk * 512 + w * 16 + lane15) * 64 + q8;
        kf0 = *reinterpret_cast<const float4*>(key + g);
        kf1 = *reinterpret_cast<const float4*>(key + g + 4);
        kf2 = *reinterpret_cast<const float4*>(key + g + 32);
        kf3 = *reinterpret_cast<const float4*>(key + g + 36);
        vf0 = *reinterpret_cast<const float4*>(value + g);
        vf1 = *reinterpret_cast<const float4*>(value + g + 4);
        vf2 = *reinterpret_cast<const float4*>(value + g + 32);
        vf3 = *reinterpret_cast<const float4*>(value + g + 36);
    }

    f32x4 ckv[4], ckvs[4];
#pragma unroll
    for (int i = 0; i < 4; ++i) {
        ckv[i]  = (f32x4){0.f, 0.f, 0.f, 0.f};
        ckvs[i] = (f32x4){0.f, 0.f, 0.f, 0.f};
    }
    float aks = 0.f, akss = 0.f;

    // projection + bias + act + transposed bf16 stores into buffer `buf`
    auto proj_store = [&](int buf, int sbase) {
        f32x4 ckp[4], cvp[4];
#pragma unroll
        for (int i = 0; i < 4; ++i) {
            ckp[i] = (f32x4){0.f, 0.f, 0.f, 0.f};
            cvp[i] = (f32x4){0.f, 0.f, 0.f, 0.f};
        }
        short8 ak0 = cvt8(kf0, kf1), ak1 = cvt8(kf2, kf3);
        short8 av0 = cvt8(vf0, vf1), av1 = cvt8(vf2, vf3);
#pragma unroll
        for (int nt = 0; nt < 4; ++nt) {
            ckp[nt] = MFMA(ak0, bkf[0][nt], ckp[nt]);
            cvp[nt] = MFMA(av0, bvf[0][nt], cvp[nt]);
            ckp[nt] = MFMA(ak1, bkf[1][nt], ckp[nt]);
            cvp[nt] = MFMA(av1, bvf[1][nt], cvp[nt]);
        }
        const int srel = w * 16 + q4;
#pragma unroll
        for (int nt = 0; nt < 4; ++nt) {
            const int x = nt * 16 + lane15;
            const float bk = sbk[x], bv = sbv[x];
            short ek[4], ev[4], es[4];
#pragma unroll
            for (int r = 0; r < 4; ++r) {
                float kk = elu1(ckp[nt][r] + bk);
                float vv = cvp[nt][r] + bv;
                ek[r] = f2bf(kk);
                ev[r] = f2bf(vv);
                es[r] = f2bf(vv * ssin[sbase + srel + r]);
            }
            st4(&kT [buf][x * 72 + srel], ek[0], ek[1], ek[2], ek[3]);
            st4(&vT [buf][x * 72 + srel], ev[0], ev[1], ev[2], ev[3]);
            st4(&vsT[buf][x * 72 + srel], es[0], es[1], es[2], es[3]);
        }
    };

    __syncthreads();           // ssin/sbk/sbv visible
    proj_store(0, 0);          // peeled: tile 0 -> buffer 0
    __syncthreads();           // buffer 0 complete

#pragma unroll 1
    for (int it = 0; it < 8; ++it) {
        const int cur = it & 1;
        // ---- prefetch next tile's K/V rows (global; overlaps everything) ----
        if (it < 7) {
            const size_t g = ((size_t)b * SS + chunk * 512 + (it + 1) * 64 + w * 16 + lane15) * 64 + q8;
            kf0 = *reinterpret_cast<const float4*>(key + g);
            kf1 = *reinterpret_cast<const float4*>(key + g + 4);
            kf2 = *reinterpret_cast<const float4*>(key + g + 32);
            kf3 = *reinterpret_cast<const float4*>(key + g + 36);
            vf0 = *reinterpret_cast<const float4*>(value + g);
            vf1 = *reinterpret_cast<const float4*>(value + g + 4);
            vf2 = *reinterpret_cast<const float4*>(value + g + 32);
            vf3 = *reinterpret_cast<const float4*>(value + g + 36);
        }
        // ---- kv / kvs GEMM from buffer cur, swapped: A=v (m=z), B=k' (n=x) ----
#pragma unroll
        for (int kstep = 0; kstep < 2; ++kstep) {
            const int so = kstep * 32;
            short8 aV  = *reinterpret_cast<const short8*>(&vT [cur][(w * 16 + lane15) * 72 + so + q8]);
            short8 aVS = *reinterpret_cast<const short8*>(&vsT[cur][(w * 16 + lane15) * 72 + so + q8]);
#pragma unroll
            for (int nt = 0; nt < 4; ++nt) {
                short8 bK = *reinterpret_cast<const short8*>(&kT[cur][(nt * 16 + lane15) * 72 + so + q8]);
                ckv[nt]  = MFMA(aV,  bK, ckv[nt]);
                ckvs[nt] = MFMA(aVS, bK, ckvs[nt]);
            }
        }
        // ---- ksum / kssum partials (thread: x = l, s-range [w*16,+16)) ----
        {
            const int sbase = it * 64;
            short8 k0 = *reinterpret_cast<const short8*>(&kT[cur][l * 72 + w * 16]);
            short8 k1 = *reinterpret_cast<const short8*>(&kT[cur][l * 72 + w * 16 + 8]);
#pragma unroll
            for (int e = 0; e < 8; ++e) {
                float fa = bf2f(k0[e]), fb = bf2f(k1[e]);
                aks  += fa + fb;
                akss += fa * ssin[sbase + w * 16 + e] + fb * ssin[sbase + w * 16 + 8 + e];
            }
        }
        // ---- project tile it+1 into the other buffer (same interval) ----
        if (it < 7) proj_store(cur ^ 1, (it + 1) * 64);
        __syncthreads();
    }

    // ---- commit: coalesced non-atomic partial stores ([z][x], x = lane15) ----
    const int bh = b * HH + h;
    const size_t pbase = ((size_t)(chunk * 64) + bh) * 4096;
#pragma unroll
    for (int nt = 0; nt < 4; ++nt) {
        const int x = nt * 16 + lane15;
#pragma unroll
        for (int r = 0; r < 4; ++r) {
            const int z = w * 16 + q4 + r;
            pkv [pbase + z * 64 + x] = ckv[nt][r];
            pkvs[pbase + z * 64 + x] = ckvs[nt][r];
        }
    }
    sred[t] = aks; sred[256 + t] = akss;
    __syncthreads();
    if (t < 64) {
        pks[((size_t)(chunk * 64) + bh) * 128 + t] =
            sred[t] + sred[64 + t] + sred[128 + t] + sred[192 + t];
    } else if (t < 128) {
        int tt = t - 64;
        pks[((size_t)(chunk * 64) + bh) * 128 + t] =
            sred[256 + tt] + sred[320 + tt] + sred[384 + tt] + sred[448 + tt];
    }
}

// ---------------------------------------------------------------------------
// Reduce 8 chunk partials -> bf16 kv/kvs + fp32 ksums.
__global__ __launch_bounds__(256) void k_reduce(
    const float* __restrict__ pkv, const float* __restrict__ pkvs,
    const float* __restrict__ pks,
    short* __restrict__ kvb, short* __restrict__ kvsb,
    float* __restrict__ ksums)
{
    const int blk = blockIdx.x, t = threadIdx.x;
    if (blk < 512) {
        const float* src = (blk < 256) ? pkv : pkvs;
        short* dst = (blk < 256) ? kvb : kvsb;
        const int o4 = (blk & 255) * 256 + t;          // float4 index, 0..65535
        float4 s = make_float4(0.f, 0.f, 0.f, 0.f);
#pragma unroll
        for (int c = 0; c < 8; ++c) {
            float4 v = reinterpret_cast<const float4*>(src + (size_t)c * 262144)[o4];
            s.x += v.x; s.y += v.y; s.z += v.z; s.w += v.w;
        }
        st4(dst + (size_t)o4 * 4, f2bf(s.x), f2bf(s.y), f2bf(s.z), f2bf(s.w));
    } else {
        const int g = (blk - 512) * 256 + t;           // float4 index, 0..2047
        float4 s = make_float4(0.f, 0.f, 0.f, 0.f);
#pragma unroll
        for (int c = 0; c < 8; ++c) {
            float4 v = reinterpret_cast<const float4*>(pks + (size_t)c * 8192)[g];
            s.x += v.x; s.y += v.y; s.z += v.z; s.w += v.w;
        }
        reinterpret_cast<float4*>(ksums)[g] = s;
    }
}

// ---------------------------------------------------------------------------
// Phase 2: R2 body VERBATIM (96-reg regime, (256,2) -> no cap, no spill),
// heads split into 2 groups of 8 across blockIdx.y -> grid 1024 blocks for
// ~3 blocks/CU residency. Per-group dense partials go to WORKSPACE with plain
// coalesced float4 stores (pout aliases the pkv region, dead after k_reduce);
// a trivial k_combine kernel sums the 2 partials + dense_b. NO atomics (R7's
// 64 MB write-through poison).
__global__ __launch_bounds__(256, 2) void k_phase2(
    const float* __restrict__ query, const float* __restrict__ wq_b,
    const short* __restrict__ wqTb,
    const short* __restrict__ kvb, const short* __restrict__ kvsb,
    const float* __restrict__ ksums,
    const short* __restrict__ wdTb,
    float* __restrict__ pout)
{
    const int st = blockIdx.x, g = blockIdx.y, b = blockIdx.z;
    const int s0 = st * 32;
    const int t = threadIdx.x, w = t >> 6, l = t & 63;
    const int lane15 = l & 15, q8 = (l >> 4) * 8, q4 = (l >> 4) * 4;

    // LDS union: compute = sqin[32][72] | per-wave sqp[32][72] | per-wave sO[16][72]
    //            reduce view = per-wave float red[32][68]
    __shared__ __align__(16) char smem[34816];
    __shared__ float scc[32];
    short* sqin = reinterpret_cast<short*>(smem);                    // [32][72]
    short* sqp  = reinterpret_cast<short*>(smem) + 2304 * (1 + w);   // wave's q' [32][72]
    short* sOw  = reinterpret_cast<short*>(smem) + 2304 * 5 + 1152 * w;  // wave's O [16][72]

    // stage q tile (fp32 -> bf16, s-major): 256 thr x 8 floats = 32x64
    {
        const int row = t >> 3, c8 = (t & 7) * 8;
        const float* qp = query + ((size_t)b * SS + s0 + row) * 64 + c8;
        float4 f0 = *reinterpret_cast<const float4*>(qp);
        float4 f1 = *reinterpret_cast<const float4*>(qp + 4);
        *reinterpret_cast<short8*>(&sqin[row * 72 + c8]) = cvt8(f0, f1);
    }
    if (t < 32) {
        float p = PI_C * (float)(s0 + t) * (1.f / 4096.f);
        scc[t] = __cosf(p) + __sinf(p);
    }
    f32x4 cd[2][4];
#pragma unroll
    for (int rt = 0; rt < 2; ++rt)
#pragma unroll
        for (int nt = 0; nt < 4; ++nt) cd[rt][nt] = (f32x4){0.f, 0.f, 0.f, 0.f};
    __syncthreads();   // q tile + scc ready (only barrier before epilogue)

    // hoisted head-independent values
    short8 aq[2][2];   // q^T B-frags for the 2 row-tiles
#pragma unroll
    for (int rt = 0; rt < 2; ++rt)
#pragma unroll
        for (int kss = 0; kss < 2; ++kss)
            aq[rt][kss] = *reinterpret_cast<const short8*>(&sqin[(rt * 16 + lane15) * 72 + kss * 32 + q8]);
    const float ccs0 = scc[lane15], ccs1 = scc[16 + lane15];  // cos+sin for s-col
    const int drow = l >> 1, dxh = (l & 1) * 32;              // denominator row / x-half
    const float ccr = scc[drow];

#pragma unroll 1
    for (int i = 0; i < 2; ++i) {
        const int h = (g << 3) | (i << 2) | w;
        const size_t bh = (size_t)(b * HH + h);
        const short* wqh = wqTb + (size_t)h * 4096;
        const short* wdh = wdTb + (size_t)h * 4096;
        const short* kv1 = kvb  + bh * 4096;
        const short* kv2 = kvsb + bh * 4096;

        // ---- Q projection, SWAPPED (A=wq^T, B=q^T): lane x=nt*16+q4+r, s=rt*16+lane15 ----
        f32x4 cq[2][4];
#pragma unroll
        for (int rt = 0; rt < 2; ++rt)
#pragma unroll
            for (int nt = 0; nt < 4; ++nt) cq[rt][nt] = (f32x4){0.f, 0.f, 0.f, 0.f};
#pragma unroll
        for (int nt = 0; nt < 4; ++nt) {
            short8 b0 = *reinterpret_cast<const short8*>(wqh + (nt * 16 + lane15) * 64 + q8);
            short8 b1 = *reinterpret_cast<const short8*>(wqh + (nt * 16 + lane15) * 64 + 32 + q8);
            cq[0][nt] = MFMA(b0, aq[0][0], cq[0][nt]);
            cq[1][nt] = MFMA(b0, aq[1][0], cq[1][nt]);
            cq[0][nt] = MFMA(b1, aq[0][1], cq[0][nt]);
            cq[1][nt] = MFMA(b1, aq[1][1], cq[1][nt]);
        }
        // bias + elu, store q' s-major
#pragma unroll
        for (int nt = 0; nt < 4; ++nt) {
            float4 bq = *reinterpret_cast<const float4*>(wq_b + h * 64 + nt * 16 + q4);
#pragma unroll
            for (int rt = 0; rt < 2; ++rt) {
                short e0 = f2bf(elu1(cq[rt][nt][0] + bq.x));
                short e1 = f2bf(elu1(cq[rt][nt][1] + bq.y));
                short e2 = f2bf(elu1(cq[rt][nt][2] + bq.z));
                short e3 = f2bf(elu1(cq[rt][nt][3] + bq.w));
                st4(&sqp[(rt * 16 + lane15) * 72 + nt * 16 + q4], e0, e1, e2, e3);
            }
        }

        // ---- denominator: lane covers row drow, x-half dxh (32 terms) ----
        float invs0, invs1;
        {
            const float* kp = ksums + bh * 128 + dxh;
            float4 A[8], Bv[8];
#pragma unroll
            for (int j = 0; j < 8; ++j) {
                A[j]  = *reinterpret_cast<const float4*>(kp + j * 4);
                Bv[j] = *reinterpret_cast<const float4*>(kp + 64 + j * 4);
            }
            short8 qr[4];
#pragma unroll
            for (int e = 0; e < 4; ++e)
                qr[e] = *reinterpret_cast<const short8*>(&sqp[drow * 72 + dxh + e * 8]);
            float dsum = 0.f;
#pragma unroll
            for (int j4 = 0; j4 < 8; ++j4)
#pragma unroll
                for (int e4 = 0; e4 < 4; ++e4)
                    dsum += bf2f(qr[j4 >> 1][(j4 & 1) * 4 + e4]) * (A[j4][e4] + ccr * Bv[j4][e4]);
            dsum += __shfl_xor(dsum, 1);
            float invd = 1.f / (dsum + 1e-5f);
            invs0 = __shfl(invd, lane15 * 2);
            invs1 = __shfl(invd, (16 + lane15) * 2);
        }

        // ---- numerator, SWAPPED (A=kv^T, B=q'^T): lane z=nt*16+q4+r, s=rt*16+lane15 ----
        short8 qf[2][2];
#pragma unroll
        for (int rt = 0; rt < 2; ++rt)
#pragma unroll
            for (int kss = 0; kss < 2; ++kss)
                qf[rt][kss] = *reinterpret_cast<const short8*>(&sqp[(rt * 16 + lane15) * 72 + kss * 32 + q8]);
        f32x4 cv1[2][4], cv2[2][4];
#pragma unroll
        for (int rt = 0; rt < 2; ++rt)
#pragma unroll
            for (int nt = 0; nt < 4; ++nt) {
                cv1[rt][nt] = (f32x4){0.f, 0.f, 0.f, 0.f};
                cv2[rt][nt] = (f32x4){0.f, 0.f, 0.f, 0.f};
            }
#pragma unroll
        for (int nt = 0; nt < 4; ++nt) {
            const short* a1 = kv1 + (nt * 16 + lane15) * 64;
            const short* a2 = kv2 + (nt * 16 + lane15) * 64;
            short8 f10 = *reinterpret_cast<const short8*>(a1 + q8);
            short8 f11 = *reinterpret_cast<const short8*>(a1 + 32 + q8);
            short8 f20 = *reinterpret_cast<const short8*>(a2 + q8);
            short8 f21 = *reinterpret_cast<const short8*>(a2 + 32 + q8);
#pragma unroll
            for (int rt = 0; rt < 2; ++rt) {
                cv1[rt][nt] = MFMA(f10, qf[rt][0], cv1[rt][nt]);
                cv1[rt][nt] = MFMA(f11, qf[rt][1], cv1[rt][nt]);
                cv2[rt][nt] = MFMA(f20, qf[rt][0], cv2[rt][nt]);
                cv2[rt][nt] = MFMA(f21, qf[rt][1], cv2[rt][nt]);
            }
        }
        // dense B-frags (reused across both row-tiles)
        short8 wdf[4][2];
#pragma unroll
        for (int nt = 0; nt < 4; ++nt)
#pragma unroll
            for (int kss = 0; kss < 2; ++kss)
                wdf[nt][kss] = *reinterpret_cast<const short8*>(wdh + (nt * 16 + lane15) * 64 + kss * 32 + q8);

        // ---- per row-tile: combine -> O scratch -> dense GEMM ----
#pragma unroll
        for (int rt = 0; rt < 2; ++rt) {
            const float ccsr = rt ? ccs1 : ccs0;
            const float invr = rt ? invs1 : invs0;
#pragma unroll
            for (int nt = 0; nt < 4; ++nt) {
                short e0 = f2bf((cv1[rt][nt][0] + ccsr * cv2[rt][nt][0]) * invr);
                short e1 = f2bf((cv1[rt][nt][1] + ccsr * cv2[rt][nt][1]) * invr);
                short e2 = f2bf((cv1[rt][nt][2] + ccsr * cv2[rt][nt][2]) * invr);
                short e3 = f2bf((cv1[rt][nt][3] + ccsr * cv2[rt][nt][3]) * invr);
                st4(&sOw[lane15 * 72 + nt * 16 + q4], e0, e1, e2, e3);
            }
            short8 of0 = *reinterpret_cast<const short8*>(&sOw[lane15 * 72 + q8]);
            short8 of1 = *reinterpret_cast<const short8*>(&sOw[lane15 * 72 + 32 + q8]);
#pragma unroll
            for (int nt = 0; nt < 4; ++nt) {
                cd[rt][nt] = MFMA(of0, wdf[nt][0], cd[rt][nt]);
                cd[rt][nt] = MFMA(of1, wdf[nt][1], cd[rt][nt]);
            }
        }
    }

    // ---- cross-wave reduction of dense partials (re-alias LDS union) ----
    __syncthreads();   // all compute reads of smem done
    {
        float* red = reinterpret_cast<float*>(smem) + 2176 * w;   // [32][68]
#pragma unroll
        for (int rt = 0; rt < 2; ++rt)
#pragma unroll
            for (int nt = 0; nt < 4; ++nt)
#pragma unroll
                for (int r = 0; r < 4; ++r)
                    red[(rt * 16 + q4 + r) * 68 + nt * 16 + lane15] = cd[rt][nt][r];
    }
    __syncthreads();
    {
        const int row = t >> 3, c8 = (t & 7) * 8;
        float4 sa = make_float4(0.f, 0.f, 0.f, 0.f);
        float4 sb = make_float4(0.f, 0.f, 0.f, 0.f);
#pragma unroll
        for (int ww = 0; ww < 4; ++ww) {
            const float* red = reinterpret_cast<const float*>(smem) + 2176 * ww;
            float4 v0 = *reinterpret_cast<const float4*>(red + row * 68 + c8);
            float4 v1 = *reinterpret_cast<const float4*>(red + row * 68 + c8 + 4);
            sa.x += v0.x; sa.y += v0.y; sa.z += v0.z; sa.w += v0.w;
            sb.x += v1.x; sb.y += v1.y; sb.z += v1.z; sb.w += v1.w;
        }
        // plain coalesced partial store: pout[g][b][s][d]
        float* op = pout + (size_t)g * (BB * SS * 64)
                  + ((size_t)b * SS + s0 + row) * 64 + c8;
        *reinterpret_cast<float4*>(op)     = sa;
        *reinterpret_cast<float4*>(op + 4) = sb;
    }
}

// ---------------------------------------------------------------------------
// Combine the 2 head-group partials + dense_b -> out. 12 MB traffic, ~3 us.
__global__ __launch_bounds__(256) void k_combine(
    const float* __restrict__ pout, const float* __restrict__ dense_b,
    float* __restrict__ out)
{
    const int o = blockIdx.x * 256 + threadIdx.x;      // float4 index, 0..262143
    float4 a = reinterpret_cast<const float4*>(pout)[o];
    float4 c = reinterpret_cast<const float4*>(pout + (size_t)BB * SS * 64)[o];
    float4 db = reinterpret_cast<const float4*>(dense_b)[o & 15];
    float4 r;
    r.x = a.x + c.x + db.x;
    r.y = a.y + c.y + db.y;
    r.z = a.z + c.z + db.z;
    r.w = a.w + c.w + db.w;
    reinterpret_cast<float4*>(out)[o] = r;
}

// ---------------------------------------------------------------------------
extern "C" void kernel_launch(void* const* d_in, const int* in_sizes, int n_in,
                              void* d_out, int out_size, void* d_ws, size_t ws_size,
                              hipStream_t stream) {
    const float* query   = (const float*)d_in[0];
    const float* key     = (const float*)d_in[1];
    const float* value   = (const float*)d_in[2];
    // d_in[3] attn_mask unused
    const float* wq_w    = (const float*)d_in[4];
    const float* wq_b    = (const float*)d_in[5];
    const float* wk_w    = (const float*)d_in[6];
    const float* wk_b    = (const float*)d_in[7];
    const float* wv_w    = (const float*)d_in[8];
    const float* wv_b    = (const float*)d_in[9];
    const float* dense_w = (const float*)d_in[10];
    const float* dense_b = (const float*)d_in[11];
    float* out = (float*)d_out;

    char* ws = (char*)d_ws;
    float* pkv   = (float*)(ws);
    float* pkvs  = (float*)(ws + 8388608);
    float* pks   = (float*)(ws + 16777216);
    short* kvb   = (short*)(ws + 17039360);
    short* kvsb  = (short*)(ws + 17563648);
    float* ksums = (float*)(ws + 18087936);
    short* wT    = (short*)(ws + 18120704);  // wq|wk|wv|wd, 65536 shorts each
    short* wqTb  = wT;
    short* wkTb  = wT + 65536;
    short* wvTb  = wT + 131072;
    short* wdTb  = wT + 196608;
    // pout[2][4][4096][64] fp32 (8 MB) aliases pkv -- dead after k_reduce
    float* pout  = pkv;

    hipLaunchKernelGGL(k_prep, dim3(16, 4), dim3(256), 0, stream,
                       wq_w, wk_w, wv_w, dense_w, wT);
    hipLaunchKernelGGL(k_phase1, dim3(8, HH, BB), dim3(256), 0, stream,
                       key, value, wk_b, wv_b, wkTb, wvTb, pkv, pkvs, pks);
    hipLaunchKernelGGL(k_reduce, dim3(520), dim3(256), 0, stream,
                       pkv, pkvs, pks, kvb, kvsb, ksums);
    hipLaunchKernelGGL(k_phase2, dim3(128, 2, BB), dim3(256), 0, stream,
                       query, wq_b, wqTb, kvb, kvsb, ksums, wdTb, pout);
    hipLaunchKernelGGL(k_combine, dim3(1024), dim3(256), 0, stream,
                       pout, dense_b, out);
}